// Round 7
// baseline (140.358 us; speedup 1.0000x reference)
//
#include <hip/hip_runtime.h>

#define NUM_BINS  512
#define NUM_NODES 128
#define K_ELEMS   16384
#define N_PAIRS   1024
#define NCOPY     32

typedef float f32x4 __attribute__((ext_vector_type(4)));
typedef unsigned int   u32;
typedef unsigned short u16;

// ---------------------------------------------------------------------------
// Pass 1: per-row histogram -> PRIVATE row outputs (no global atomics, no
// pre-zero needed). Fixed-point u32 LDS atomics (ds_add_u32 = fast bank-
// parallel path; ds_add_f32 is CU-serialized ~3.3 cy/lane, measured R1-R4).
// 32 LDS copies, copy = tid&31 -> bank = copy: 2 lanes/bank, conflict-free.
// 1024 thr, 64KB LDS -> 2 blocks/CU -> 32 waves/CU.
// Emits u16 lookup-codes (rounded bin or 0xFFFF) so pass 3 never re-reads
// the 128 MiB inputs. Inputs loaded non-temporally (read-once).
// ---------------------------------------------------------------------------
__global__ __launch_bounds__(1024) void hist_kernel(
    const float* __restrict__ residuals, const float* __restrict__ weights,
    u32* __restrict__ rowhist, float* __restrict__ rowwsum,
    u16* __restrict__ codes)
{
    __shared__ u32 lh[NUM_BINS * NCOPY];   // 65536 bytes
    __shared__ float swsum[16];
    const int row  = blockIdx.x;
    const int t    = threadIdx.x;          // 0..1023
    const int copy = t & 31;

    // zero 16384 u32: 1024 threads x 4 uint4
    uint4* lh4 = (uint4*)lh;
    #pragma unroll
    for (int k = 0; k < NUM_BINS * NCOPY / 4 / 1024; ++k) {
        uint4 z; z.x = z.y = z.z = z.w = 0u;
        lh4[t + k * 1024] = z;
    }
    __syncthreads();

    const f32x4* r4 = (const f32x4*)(residuals + (size_t)row * K_ELEMS);
    const f32x4* w4 = (const f32x4*)(weights   + (size_t)row * K_ELEMS);
    ushort4*     c4 = (ushort4*)(codes + (size_t)row * K_ELEMS);

    float wsum = 0.0f;
    // 4096 float4 per row / 1024 threads = 4 iterations
    #pragma unroll
    for (int it = 0; it < K_ELEMS / 4 / 1024; ++it) {
        f32x4 r = __builtin_nontemporal_load(r4 + (t + it * 1024));
        f32x4 w = __builtin_nontemporal_load(w4 + (t + it * 1024));
        wsum += w[0] + w[1] + w[2] + w[3];     // tw is UNMASKED sum

        ushort4 cv;
        u16* cp = (u16*)&cv;
        #pragma unroll
        for (int c = 0; c < 4; ++c) {
            int b = (int)floorf(r[c] * 512.0f);
            if ((unsigned)b < 512u)
                atomicAdd(&lh[b * NCOPY + copy], (u32)fmaf(w[c], 65536.0f, 0.5f));
            int lb = (int)floorf(r[c] * 512.0f + 0.5f);
            cp[c] = (u16)((((unsigned)lb < 512u) & (w[c] > 0.0f)) ? lb : 0xFFFF);
        }
        c4[t + it * 1024] = cv;
    }

    // block weight total
    #pragma unroll
    for (int off = 32; off > 0; off >>= 1) wsum += __shfl_down(wsum, off, 64);
    const int wave = t >> 6, lane = t & 63;
    if (lane == 0) swsum[wave] = wsum;
    __syncthreads();

    if (t == 0) {
        float tot = 0.0f;
        #pragma unroll
        for (int i = 0; i < 16; ++i) tot += swsum[i];
        rowwsum[row] = tot;
    }

    // flush: thread pair (2b,2b+1) owns bin b; each sums 16 of the 32 copies
    // (rotated -> 2 lanes/bank, free), combines via shfl, even half stores.
    {
        const int bin  = t >> 1;
        const int half = t & 1;
        u32 tot = 0;
        #pragma unroll
        for (int cc = 0; cc < 16; ++cc)
            tot += lh[bin * NCOPY + (((bin + cc) & 15) | (half << 4))];
        tot += (u32)__shfl_xor((int)tot, 1);
        if (half == 0) rowhist[(size_t)row * NUM_BINS + bin] = tot;
    }
}

// ---------------------------------------------------------------------------
// Pass 2: per-node gather of matching rows (mult = (s==n)+(d==n), matching
// the ref's double-add when s==d), pmf = hist/(tw+1e-10), inclusive scan.
// One block (512 thr) per node. Row loop is block-uniform -> cheap skips.
// ---------------------------------------------------------------------------
__global__ __launch_bounds__(512) void scan_kernel(
    const u32* __restrict__ rowhist, const float* __restrict__ rowwsum,
    const int* __restrict__ src, const int* __restrict__ dst,
    float* __restrict__ cdf)
{
    __shared__ float s[NUM_BINS];
    __shared__ int ssrc[N_PAIRS];
    __shared__ int sdst[N_PAIRS];
    const int node = blockIdx.x;
    const int t    = threadIdx.x;

    for (int i = t; i < N_PAIRS; i += 512) {
        ssrc[i] = src[i];
        sdst[i] = dst[i];
    }
    __syncthreads();

    float acc = 0.0f, twf = 0.0f;
    for (int r = 0; r < N_PAIRS; ++r) {
        const int m = (ssrc[r] == node) + (sdst[r] == node);
        if (m) {   // block-uniform branch
            acc += (float)m * (float)rowhist[(size_t)r * NUM_BINS + t];
            twf += (float)m * rowwsum[r];
        }
    }

    const float denom = twf + 1e-10f;
    s[t] = acc * (1.0f / 65536.0f) / denom;
    __syncthreads();

    for (int off = 1; off < NUM_BINS; off <<= 1) {
        float add = (t >= off) ? s[t - off] : 0.0f;
        __syncthreads();
        s[t] += add;
        __syncthreads();
    }
    cdf[node * NUM_BINS + t] = s[t];
}

// ---------------------------------------------------------------------------
// Pass 3: lookup from u16 codes; cdf rows staged in LDS; non-temporal output
// stores (write-once stream, keep L3 for codes).
// ---------------------------------------------------------------------------
__global__ __launch_bounds__(256) void lookup_code_kernel(
    const u16* __restrict__ codes,
    const int* __restrict__ src, const int* __restrict__ dst,
    const float* __restrict__ cdf,
    float* __restrict__ out_src, float* __restrict__ out_dst)
{
    __shared__ float scdf[NUM_BINS];
    __shared__ float dcdf[NUM_BINS];
    const int CHUNK = K_ELEMS / 4;          // 4096 elements per block
    const int row   = blockIdx.x >> 2;
    const int chunk = blockIdx.x & 3;
    const int t     = threadIdx.x;

    const int s = src[row], d = dst[row];
    for (int i = t; i < NUM_BINS; i += 256) {
        scdf[i] = cdf[s * NUM_BINS + i];
        dcdf[i] = cdf[d * NUM_BINS + i];
    }
    __syncthreads();

    const size_t base = (size_t)row * K_ELEMS + (size_t)chunk * CHUNK;
    const ushort4* c4 = (const ushort4*)(codes + base);
    f32x4*        os4 = (f32x4*)(out_src + base);
    f32x4*        od4 = (f32x4*)(out_dst + base);

    for (int i = t; i < CHUNK / 4; i += 256) {   // 4 iters
        ushort4 c = c4[i];
        f32x4 osv, odv;
        osv[0] = (c.x != 0xFFFF) ? scdf[c.x] : 2.0f;
        odv[0] = (c.x != 0xFFFF) ? dcdf[c.x] : 2.0f;
        osv[1] = (c.y != 0xFFFF) ? scdf[c.y] : 2.0f;
        odv[1] = (c.y != 0xFFFF) ? dcdf[c.y] : 2.0f;
        osv[2] = (c.z != 0xFFFF) ? scdf[c.z] : 2.0f;
        odv[2] = (c.z != 0xFFFF) ? dcdf[c.z] : 2.0f;
        osv[3] = (c.w != 0xFFFF) ? scdf[c.w] : 2.0f;
        odv[3] = (c.w != 0xFFFF) ? dcdf[c.w] : 2.0f;
        __builtin_nontemporal_store(osv, os4 + i);
        __builtin_nontemporal_store(odv, od4 + i);
    }
}

// ---------------------------------------------------------------------------
extern "C" void kernel_launch(void* const* d_in, const int* in_sizes, int n_in,
                              void* d_out, int out_size, void* d_ws, size_t ws_size,
                              hipStream_t stream)
{
    const float* residuals = (const float*)d_in[0];
    const float* weights   = (const float*)d_in[1];
    const int*   src       = (const int*)d_in[2];
    const int*   dst       = (const int*)d_in[3];

    float* out_src = (float*)d_out;
    float* out_dst = out_src + (size_t)N_PAIRS * K_ELEMS;

    // workspace layout (observed ws_size ~512 MiB; we use ~36 MiB):
    //   [0,        2 MiB)  rowhist  u32[1024][512]
    //   [2 MiB,   +4 KiB)  rowwsum  f32[1024]
    //   [2M+8K,  +256 KiB) cdf      f32[128][512]
    //   [4 MiB,  +32 MiB)  codes    u16[1024*16384]
    char* ws = (char*)d_ws;
    u32*   rowhist = (u32*)ws;
    float* rowwsum = (float*)(ws + (2u << 20));
    float* cdf     = (float*)(ws + (2u << 20) + 8192);
    u16*   codes   = (u16*)(ws + (4u << 20));

    hist_kernel<<<N_PAIRS, 1024, 0, stream>>>(residuals, weights,
                                              rowhist, rowwsum, codes);

    scan_kernel<<<NUM_NODES, NUM_BINS, 0, stream>>>(rowhist, rowwsum,
                                                    src, dst, cdf);

    lookup_code_kernel<<<N_PAIRS * 4, 256, 0, stream>>>(codes, src, dst, cdf,
                                                        out_src, out_dst);
}

// Round 8
// 68.906 us; speedup vs baseline: 2.0369x; 2.0369x over previous
//
#include <hip/hip_runtime.h>

#define NUM_BINS  512
#define NUM_NODES 128
#define K_ELEMS   16384
#define N_PAIRS   1024
#define NCOPY     32

typedef float f32x4 __attribute__((ext_vector_type(4)));
typedef unsigned int   u32;
typedef unsigned short u16;

__device__ __forceinline__ void gfadd(float* p, float v) { unsafeAtomicAdd(p, v); }

// ---------------------------------------------------------------------------
// Pass 0: zero node hist + tw (65,664 floats, ~1us).
// ---------------------------------------------------------------------------
__global__ __launch_bounds__(256) void zero_ws_kernel(float* __restrict__ ws, int n)
{
    int i = blockIdx.x * 256 + threadIdx.x;
    if (i < n) ws[i] = 0.0f;
}

// ---------------------------------------------------------------------------
// Pass 1: per-row histogram. Fixed-point u32 LDS atomics (ds_add_u32 is the
// fast bank-parallel path; ds_add_f32 is CU-serialized ~3.3 cy/lane, measured
// R1-R4). 32 copies, copy = tid&31 -> bank = copy: 2 lanes/bank (free).
// 1024 thr, 64KB LDS -> 2 blocks/CU -> 32 waves/CU.
// Flush: coalesced global float atomics to hist[src],hist[dst] (R6-proven;
// the R7 per-row-then-gather variant was an 83us latency disaster).
// Emits u16 lookup-codes so pass 3 never re-reads the 128 MiB inputs.
// Inputs loaded non-temporally (read-once; keep L2/L3 for codes).
// ---------------------------------------------------------------------------
__global__ __launch_bounds__(1024) void hist_kernel(
    const float* __restrict__ residuals, const float* __restrict__ weights,
    const int* __restrict__ src, const int* __restrict__ dst,
    float* __restrict__ hist, float* __restrict__ tw,
    u16* __restrict__ codes)
{
    __shared__ u32 lh[NUM_BINS * NCOPY];   // 65536 bytes
    __shared__ float swsum[16];
    const int row  = blockIdx.x;
    const int t    = threadIdx.x;          // 0..1023
    const int copy = t & 31;

    // zero 16384 u32: 1024 threads x 4 uint4
    uint4* lh4 = (uint4*)lh;
    #pragma unroll
    for (int k = 0; k < NUM_BINS * NCOPY / 4 / 1024; ++k) {
        uint4 z; z.x = z.y = z.z = z.w = 0u;
        lh4[t + k * 1024] = z;
    }
    __syncthreads();

    const f32x4* r4 = (const f32x4*)(residuals + (size_t)row * K_ELEMS);
    const f32x4* w4 = (const f32x4*)(weights   + (size_t)row * K_ELEMS);
    ushort4*     c4 = (ushort4*)(codes + (size_t)row * K_ELEMS);

    float wsum = 0.0f;
    // 4096 float4 per row / 1024 threads = 4 iterations
    #pragma unroll
    for (int it = 0; it < K_ELEMS / 4 / 1024; ++it) {
        f32x4 r = __builtin_nontemporal_load(r4 + (t + it * 1024));
        f32x4 w = __builtin_nontemporal_load(w4 + (t + it * 1024));
        wsum += w[0] + w[1] + w[2] + w[3];     // tw is UNMASKED sum

        ushort4 cv;
        u16* cp = (u16*)&cv;
        #pragma unroll
        for (int c = 0; c < 4; ++c) {
            int b = (int)floorf(r[c] * 512.0f);
            if ((unsigned)b < 512u)
                atomicAdd(&lh[b * NCOPY + copy], (u32)fmaf(w[c], 65536.0f, 0.5f));
            int lb = (int)floorf(r[c] * 512.0f + 0.5f);
            cp[c] = (u16)((((unsigned)lb < 512u) & (w[c] > 0.0f)) ? lb : 0xFFFF);
        }
        c4[t + it * 1024] = cv;
    }

    // block weight total
    #pragma unroll
    for (int off = 32; off > 0; off >>= 1) wsum += __shfl_down(wsum, off, 64);
    const int wave = t >> 6, lane = t & 63;
    if (lane == 0) swsum[wave] = wsum;
    __syncthreads();

    const int s = src[row], d = dst[row];
    if (t == 0) {
        float tot = 0.0f;
        #pragma unroll
        for (int i = 0; i < 16; ++i) tot += swsum[i];
        gfadd(&tw[s], tot);
        gfadd(&tw[d], tot);   // both, even if s == d (matches ref)
    }

    // flush: thread pair (2b,2b+1) owns bin b; each sums 16 of the 32 copies
    // (rotated -> 2 lanes/bank, free), combines via shfl; even half -> src,
    // odd half -> dst. Coalesced global float atomics.
    {
        const int bin  = t >> 1;
        const int half = t & 1;
        u32 tot = 0;
        #pragma unroll
        for (int cc = 0; cc < 16; ++cc)
            tot += lh[bin * NCOPY + (((bin + cc) & 15) | (half << 4))];
        tot += (u32)__shfl_xor((int)tot, 1);
        float v = (float)tot * (1.0f / 65536.0f);
        if (half == 0) gfadd(&hist[s * NUM_BINS + bin], v);
        else           gfadd(&hist[d * NUM_BINS + bin], v);
    }
}

// ---------------------------------------------------------------------------
// Pass 2: pmf = hist / (tw + 1e-10); cdf = inclusive scan. In-place on hist.
// One block (512 thr) per node; Hillis-Steele in LDS. ~3us.
// ---------------------------------------------------------------------------
__global__ __launch_bounds__(512) void scan_kernel(float* __restrict__ hist,
                                                   const float* __restrict__ tw)
{
    __shared__ float s[NUM_BINS];
    const int node = blockIdx.x;
    const int t    = threadIdx.x;

    const float denom = tw[node] + 1e-10f;
    s[t] = hist[node * NUM_BINS + t] / denom;
    __syncthreads();

    for (int off = 1; off < NUM_BINS; off <<= 1) {
        float add = (t >= off) ? s[t - off] : 0.0f;
        __syncthreads();
        s[t] += add;
        __syncthreads();
    }
    hist[node * NUM_BINS + t] = s[t];
}

// ---------------------------------------------------------------------------
// Pass 3: lookup from u16 codes; cdf rows staged in LDS; non-temporal output
// stores (write-once stream; keep L2/L3 for codes).
// ---------------------------------------------------------------------------
__global__ __launch_bounds__(256) void lookup_code_kernel(
    const u16* __restrict__ codes,
    const int* __restrict__ src, const int* __restrict__ dst,
    const float* __restrict__ cdf,
    float* __restrict__ out_src, float* __restrict__ out_dst)
{
    __shared__ float scdf[NUM_BINS];
    __shared__ float dcdf[NUM_BINS];
    const int CHUNK = K_ELEMS / 4;          // 4096 elements per block
    const int row   = blockIdx.x >> 2;
    const int chunk = blockIdx.x & 3;
    const int t     = threadIdx.x;

    const int s = src[row], d = dst[row];
    for (int i = t; i < NUM_BINS; i += 256) {
        scdf[i] = cdf[s * NUM_BINS + i];
        dcdf[i] = cdf[d * NUM_BINS + i];
    }
    __syncthreads();

    const size_t base = (size_t)row * K_ELEMS + (size_t)chunk * CHUNK;
    const ushort4* c4 = (const ushort4*)(codes + base);
    f32x4*        os4 = (f32x4*)(out_src + base);
    f32x4*        od4 = (f32x4*)(out_dst + base);

    for (int i = t; i < CHUNK / 4; i += 256) {   // 4 iters
        ushort4 c = c4[i];
        f32x4 osv, odv;
        osv[0] = (c.x != 0xFFFF) ? scdf[c.x] : 2.0f;
        odv[0] = (c.x != 0xFFFF) ? dcdf[c.x] : 2.0f;
        osv[1] = (c.y != 0xFFFF) ? scdf[c.y] : 2.0f;
        odv[1] = (c.y != 0xFFFF) ? dcdf[c.y] : 2.0f;
        osv[2] = (c.z != 0xFFFF) ? scdf[c.z] : 2.0f;
        odv[2] = (c.z != 0xFFFF) ? dcdf[c.z] : 2.0f;
        osv[3] = (c.w != 0xFFFF) ? scdf[c.w] : 2.0f;
        odv[3] = (c.w != 0xFFFF) ? dcdf[c.w] : 2.0f;
        __builtin_nontemporal_store(osv, os4 + i);
        __builtin_nontemporal_store(odv, od4 + i);
    }
}

// ---------------------------------------------------------------------------
extern "C" void kernel_launch(void* const* d_in, const int* in_sizes, int n_in,
                              void* d_out, int out_size, void* d_ws, size_t ws_size,
                              hipStream_t stream)
{
    const float* residuals = (const float*)d_in[0];
    const float* weights   = (const float*)d_in[1];
    const int*   src       = (const int*)d_in[2];
    const int*   dst       = (const int*)d_in[3];

    float* out_src = (float*)d_out;
    float* out_dst = out_src + (size_t)N_PAIRS * K_ELEMS;

    // workspace layout (ws ~512 MiB; we use ~36 MiB):
    //   [0,       256 KiB)  hist f32[128][512] (becomes cdf in place)
    //   [256 KiB, +512 B )  tw   f32[128]
    //   [4 MiB,  +32 MiB )  codes u16[1024*16384]
    char* ws = (char*)d_ws;
    float* hist  = (float*)ws;
    float* tw    = (float*)(ws + NUM_NODES * NUM_BINS * 4);
    u16*   codes = (u16*)(ws + (4u << 20));

    const int ws_elems = NUM_NODES * NUM_BINS + NUM_NODES;
    zero_ws_kernel<<<(ws_elems + 255) / 256, 256, 0, stream>>>((float*)d_ws, ws_elems);

    hist_kernel<<<N_PAIRS, 1024, 0, stream>>>(residuals, weights, src, dst,
                                              hist, tw, codes);

    scan_kernel<<<NUM_NODES, NUM_BINS, 0, stream>>>(hist, tw);

    lookup_code_kernel<<<N_PAIRS * 4, 256, 0, stream>>>(codes, src, dst, hist,
                                                        out_src, out_dst);
}